// Round 5
// baseline (57.843 us; speedup 1.0000x reference)
//
#include <hip/hip_runtime.h>

// WordPooler, single fused kernel with block-local word ownership.
// Offsets sorted ascending per row (PAD=-100 only in the tail) -> each word is
// one run -> reference's scatter-mean == "copy first subword row, else zeros".
//
// Block (b, k) owns tokens [s0, s0+TOK) and therefore words
// (ofs[s0-1], last_valid_in_window]: sortedness guarantees every word in that
// range has its FIRST token inside the window, and consecutive blocks' ranges
// tile [0, T-1] disjointly (PAD-transition block ends at T-1 since the problem
// guarantees max offset == T-1; fully-PAD windows see ofs[s0-1]=PAD and exit).
// Phase A: 17-int coalesced load -> LDS.  Phase B: per owned word, 5-step
// binary search over the 17-entry LDS window (no global dependent chain).
// Phase C: one wave per word, 4x independent float4 copy or zero-fill.
// One dispatch, no workspace, no inter-block communication.

typedef float v4f __attribute__((ext_vector_type(4)));

#define TOK 16      // tokens per block
#define WCAP 256    // words processed per chunk (nw > WCAP is ~impossible here)

__global__ void __launch_bounds__(256)
wp_fused(const float* __restrict__ hs, const int* __restrict__ ofs,
         float* __restrict__ out, int S, int T, int D) {
    const int b   = blockIdx.y;
    const int s0  = blockIdx.x * TOK;
    const int tid = threadIdx.x;
    const int* __restrict__ row = ofs + (size_t)b * S;

    __shared__ int w_ofs[TOK + 1];   // w_ofs[j] = ofs[s0-1+j], j=0..TOK
    __shared__ int w_src[WCAP];

    if (tid <= TOK) {
        int idx = s0 - 1 + tid;
        w_ofs[tid] = (idx < 0) ? -1 : row[idx];
    }
    __syncthreads();

    const int v_before = w_ofs[0];
    if (v_before < -1) return;               // window entirely in PAD tail

    const int lane = tid & 63;
    const int wave = tid >> 6;

    // Highest valid index in window via ballot (identical in every wave).
    const bool my_valid = (lane < TOK) && (w_ofs[lane + 1] >= 0);
    const unsigned long long mask = __ballot(my_valid);
    if (mask == 0ULL) return;                // no valid tokens in window
    const int j_last = (63 - __clzll(mask)) + 1;
    const int v_last = w_ofs[j_last];
    const int nw = v_last - v_before;        // owned words: (v_before, v_last]
    if (nw <= 0) return;

    const int nv = D >> 2;                   // float4 per row

    for (int base = 0; base < nw; base += WCAP) {
        const int lim = (nw - base < WCAP) ? (nw - base) : WCAP;

        __syncthreads();
        // Phase B: locate each owned word inside the LDS window.
        for (int wi = tid; wi < lim; wi += 256) {
            const int w = v_before + 1 + base + wi;
            int lo = 1, hi = TOK + 1;
            while (lo < hi) {
                int mid = (lo + hi) >> 1;
                int v = w_ofs[mid];
                int key = (v < 0) ? 0x7fffffff : v;   // PAD -> +inf
                if (key < w) lo = mid + 1; else hi = mid;
            }
            const bool hit = (lo <= TOK) && (w_ofs[lo] == w);
            w_src[wi] = hit ? (s0 - 1 + lo) : -1;
        }
        __syncthreads();

        // Phase C: one wave per owned word.
        for (int wi = wave; wi < lim; wi += 4) {
            const int s = w_src[wi];                       // LDS broadcast
            const int t = v_before + 1 + base + wi;
            v4f* __restrict__ o = (v4f*)(out + ((size_t)b * T + t) * (size_t)D);
            if (s >= 0) {
                const v4f* __restrict__ in =
                    (const v4f*)(hs + ((size_t)b * S + s) * (size_t)D);
                #pragma unroll 4
                for (int j = lane; j < nv; j += 64) o[j] = in[j];
            } else {
                const v4f z = (v4f)(0.f);
                #pragma unroll 4
                for (int j = lane; j < nv; j += 64) o[j] = z;
            }
        }
    }
}

extern "C" void kernel_launch(void* const* d_in, const int* in_sizes, int n_in,
                              void* d_out, int out_size, void* d_ws, size_t ws_size,
                              hipStream_t stream) {
    const float* hs  = (const float*)d_in[0];   // (B,S,D) f32
    const int*   ofs = (const int*)d_in[1];     // (B,S) int32
    float* out = (float*)d_out;                 // (B,T,D) f32

    const int B = 8;
    const int BS = in_sizes[1];
    const int S = BS / B;
    const int D = in_sizes[0] / BS;
    const int T = out_size / (B * D);

    dim3 grid(S / TOK, B);                      // 256 x 8 = 2048 blocks
    wp_fused<<<grid, 256, 0, stream>>>(hs, ofs, out, S, T, D);
}

// Round 6
// 40.899 us; speedup vs baseline: 1.4143x; 1.4143x over previous
//
#include <hip/hip_runtime.h>

// WordPooler, single-dispatch pure scatter.
// Offsets sorted ascending per row (PAD=-100 only in the tail) -> each word is
// one run -> reference's scatter-mean == "copy first subword row, else zeros".
//
// One WAVE per token (b,s):
//   v = ofs[s], prev = ofs[s-1] (or -1 at s=0)
//   v>=0 && v!=prev  -> run start: zero-fill absent words (prev,v), then copy
//                       hs row s -> out word v  (unique owner of all of them)
//   v<0  && prev>=0  -> first PAD token: zero-fill (prev, T)   [tail words]
//   else             -> retire immediately
// Correctness: every word in [0,T) is written exactly once -- present words by
// their unique run start, absent words by the unique next run start (or the
// PAD transition). No scratch, no barriers, no dependent index chain: payload
// loads issue ~2 instructions after kernel entry, 32K waves resident.

typedef float v4f __attribute__((ext_vector_type(4)));

__global__ void __launch_bounds__(256)
wp_scatter_copy(const float* __restrict__ hs, const int* __restrict__ ofs,
                float* __restrict__ out, int S, int T, int D) {
    const int wave = threadIdx.x >> 6;
    const int lane = threadIdx.x & 63;
    const int s = blockIdx.x * 4 + wave;
    const int b = blockIdx.y;

    const int* __restrict__ row = ofs + (size_t)b * S;
    const int v    = row[s];
    const int prev = (s == 0) ? -1 : row[s - 1];

    const int nv = D >> 2;                       // float4 per row (256)
    const v4f z = (v4f)(0.f);

    if (v >= 0) {
        if (v == prev) return;                   // not a run start
        // Issue the row-copy loads first so they fly during any gap-fill.
        const v4f* __restrict__ in =
            (const v4f*)(hs + ((size_t)b * S + s) * (size_t)D);
        v4f r0 = in[lane];
        v4f r1 = in[lane + 64];
        v4f r2 = in[lane + 128];
        v4f r3 = in[lane + 192];
        // Zero-fill absent words (prev, v).
        for (int w = prev + 1; w < v; ++w) {
            v4f* __restrict__ o = (v4f*)(out + ((size_t)b * T + w) * (size_t)D);
            #pragma unroll 4
            for (int j = lane; j < nv; j += 64) o[j] = z;
        }
        v4f* __restrict__ o = (v4f*)(out + ((size_t)b * T + v) * (size_t)D);
        o[lane]       = r0;
        o[lane + 64]  = r1;
        o[lane + 128] = r2;
        o[lane + 192] = r3;
    } else if (prev >= 0) {
        // First PAD token: words after the last valid offset are absent.
        for (int w = prev + 1; w < T; ++w) {
            v4f* __restrict__ o = (v4f*)(out + ((size_t)b * T + w) * (size_t)D);
            #pragma unroll 4
            for (int j = lane; j < nv; j += 64) o[j] = z;
        }
    }
}

extern "C" void kernel_launch(void* const* d_in, const int* in_sizes, int n_in,
                              void* d_out, int out_size, void* d_ws, size_t ws_size,
                              hipStream_t stream) {
    const float* hs  = (const float*)d_in[0];   // (B,S,D) f32
    const int*   ofs = (const int*)d_in[1];     // (B,S) int32
    float* out = (float*)d_out;                 // (B,T,D) f32

    const int B = 8;
    const int BS = in_sizes[1];
    const int S = BS / B;
    const int D = in_sizes[0] / BS;
    const int T = out_size / (B * D);

    dim3 grid(S / 4, B);                        // one wave per token
    wp_scatter_copy<<<grid, 256, 0, stream>>>(hs, ofs, out, S, T, D);
}

// Round 7
// 28.239 us; speedup vs baseline: 2.0484x; 1.4483x over previous
//
#include <hip/hip_runtime.h>

// WordPooler, two-phase, fully-initialized index + NT stores.
// Offsets sorted ascending per row (PAD=-100 only in the tail) -> each word is
// one run -> reference's scatter-mean == "copy first subword row, else zeros".
//
// K1 (token-parallel): thread (b,s) with run-start v writes src[b,v]=s AND
//     src[b,w]=-1 for the absent words w in (prev,v) (it is their unique
//     owner by sortedness; first-PAD thread covers the tail). Every src entry
//     is (re)written every call -> K2 needs no verification, no memset node.
// K2 (wave-per-word): chain is just src load -> row copy. Stores are
//     NONTEMPORAL (write-once stream, keep it out of L2/L3) while hs loads
//     stay cached so the ~54 MiB of touched rows can sit in the 256 MiB L3
//     across graph replays. Every resident wave carries an 8 KiB payload.

typedef float v4f __attribute__((ext_vector_type(4)));

__global__ void __launch_bounds__(256)
wp_index_kernel(const int* __restrict__ ofs, int* __restrict__ src,
                int S, int T) {
    const int s = blockIdx.x * 256 + threadIdx.x;
    const int b = blockIdx.y;
    const int* __restrict__ row = ofs + (size_t)b * S;
    int* __restrict__ sb = src + (size_t)b * T;

    const int v    = row[s];
    const int prev = (s == 0) ? -1 : row[s - 1];

    if (v >= 0) {
        if (v == prev) return;                 // not a run start
        for (int w = prev + 1; w < v; ++w) sb[w] = -1;   // absent gap words
        sb[v] = s;                             // first token of word v
    } else if (prev >= 0) {
        for (int w = prev + 1; w < T; ++w) sb[w] = -1;   // absent tail words
    }
}

__global__ void __launch_bounds__(256)
wp_gather_kernel(const float* __restrict__ hs, const int* __restrict__ src,
                 float* __restrict__ out, int S, int T, int D) {
    const int wave = threadIdx.x >> 6;            // 4 waves/block
    const int lane = threadIdx.x & 63;
    const int t = blockIdx.x * 4 + wave;          // word id within batch b
    const int b = blockIdx.y;
    const size_t word = (size_t)b * T + t;
    const int s = src[word];                      // wave-uniform broadcast

    v4f* __restrict__ o = (v4f*)(out + word * (size_t)D);
    if (s >= 0) {
        const v4f* __restrict__ in =
            (const v4f*)(hs + ((size_t)b * S + s) * (size_t)D);
        v4f r0 = in[lane];
        v4f r1 = in[lane + 64];
        v4f r2 = in[lane + 128];
        v4f r3 = in[lane + 192];
        __builtin_nontemporal_store(r0, o + lane);
        __builtin_nontemporal_store(r1, o + lane + 64);
        __builtin_nontemporal_store(r2, o + lane + 128);
        __builtin_nontemporal_store(r3, o + lane + 192);
    } else {
        const v4f z = (v4f)(0.f);
        __builtin_nontemporal_store(z, o + lane);
        __builtin_nontemporal_store(z, o + lane + 64);
        __builtin_nontemporal_store(z, o + lane + 128);
        __builtin_nontemporal_store(z, o + lane + 192);
    }
}

extern "C" void kernel_launch(void* const* d_in, const int* in_sizes, int n_in,
                              void* d_out, int out_size, void* d_ws, size_t ws_size,
                              hipStream_t stream) {
    const float* hs  = (const float*)d_in[0];   // (B,S,D) f32
    const int*   ofs = (const int*)d_in[1];     // (B,S) int32
    float* out = (float*)d_out;                 // (B,T,D) f32
    int* src = (int*)d_ws;                      // (B,T) scratch

    const int B = 8;
    const int BS = in_sizes[1];
    const int S = BS / B;
    const int D = in_sizes[0] / BS;
    const int T = out_size / (B * D);

    dim3 g1(S / 256, B);
    wp_index_kernel<<<g1, 256, 0, stream>>>(ofs, src, S, T);

    dim3 g2(T / 4, B);
    wp_gather_kernel<<<g2, 256, 0, stream>>>(hs, src, out, S, T, D);
}

// Round 8
// 24.057 us; speedup vs baseline: 2.4044x; 1.1738x over previous
//
#include <hip/hip_runtime.h>

// WordPooler, single-dispatch, wave-per-word with 2-round 64-ary search.
// Offsets sorted ascending per row (PAD=-100 only in the tail) -> each word is
// one run -> reference's scatter-mean == "copy first subword row, else zeros".
//
// Each WAVE owns one output word (b,t):
//   round 1: lane i probes row[i*stride] (PAD/OOB -> +inf), ballot(key<t)
//            -> popcount n1 brackets lower_bound into a <=64-wide window
//   round 2: lane i probes row[base+i], ballot(key<t) -> lb = base + n2;
//            present iff lane n2's probe == t (bit n2 of ballot(key==t)).
//   payload: 4 independent float4 loads from hs row lb (if present) and
//            4 NT stores to out row t (zeros if absent).
// Only 2 dependent load rounds precede the payload (vs 12 for binary search),
// and all search probes are L1/L2-hot (each batch's offsets row is 16 KiB,
// shared by 2048 waves; round-1 addresses are identical across those waves).
// One dispatch: no scratch, no memset, no second node boundary.

typedef float v4f __attribute__((ext_vector_type(4)));

__global__ void __launch_bounds__(256)
wp_search_gather(const float* __restrict__ hs, const int* __restrict__ ofs,
                 float* __restrict__ out, int S, int T, int D) {
    const int wave = threadIdx.x >> 6;
    const int lane = threadIdx.x & 63;
    const int t = blockIdx.x * 4 + wave;          // word id within batch b
    const int b = blockIdx.y;

    const int* __restrict__ row = ofs + (size_t)b * S;
    const int stride = (S + 63) >> 6;             // 64 for S=4096

    // Round 1: coarse bracket. key = PAD/OOB -> +inf keeps the row monotone.
    int idx1 = lane * stride;
    int k1 = 0x7fffffff;
    if (idx1 < S) { int v = row[idx1]; k1 = (v < 0) ? 0x7fffffff : v; }
    const unsigned long long m1 = __ballot(k1 < t);
    const int n1 = __popcll(m1);
    const int base = (n1 == 0) ? 0 : (n1 - 1) * stride + 1;

    // Round 2: fine probe of 64 consecutive positions.
    // lower_bound lb satisfies base <= lb <= n1*stride <= base+63.
    int idx2 = base + lane;
    int k2 = 0x7fffffff;
    if (idx2 < S) { int v = row[idx2]; k2 = (v < 0) ? 0x7fffffff : v; }
    const unsigned long long m2  = __ballot(k2 < t);
    const unsigned long long meq = __ballot(k2 == t);
    const int n2 = __popcll(m2);
    const int lb = base + n2;                     // lower_bound position
    const bool present = (meq >> n2) & 1ULL;      // row[lb] == t ?

    v4f* __restrict__ o = (v4f*)(out + ((size_t)b * T + t) * (size_t)D);
    if (present) {
        const v4f* __restrict__ in =
            (const v4f*)(hs + ((size_t)b * S + lb) * (size_t)D);
        v4f r0 = in[lane];
        v4f r1 = in[lane + 64];
        v4f r2 = in[lane + 128];
        v4f r3 = in[lane + 192];
        __builtin_nontemporal_store(r0, o + lane);
        __builtin_nontemporal_store(r1, o + lane + 64);
        __builtin_nontemporal_store(r2, o + lane + 128);
        __builtin_nontemporal_store(r3, o + lane + 192);
    } else {
        const v4f z = (v4f)(0.f);
        __builtin_nontemporal_store(z, o + lane);
        __builtin_nontemporal_store(z, o + lane + 64);
        __builtin_nontemporal_store(z, o + lane + 128);
        __builtin_nontemporal_store(z, o + lane + 192);
    }
}

extern "C" void kernel_launch(void* const* d_in, const int* in_sizes, int n_in,
                              void* d_out, int out_size, void* d_ws, size_t ws_size,
                              hipStream_t stream) {
    const float* hs  = (const float*)d_in[0];   // (B,S,D) f32
    const int*   ofs = (const int*)d_in[1];     // (B,S) int32
    float* out = (float*)d_out;                 // (B,T,D) f32

    const int B = 8;
    const int BS = in_sizes[1];
    const int S = BS / B;
    const int D = in_sizes[0] / BS;
    const int T = out_size / (B * D);

    dim3 grid(T / 4, B);                        // one wave per word
    wp_search_gather<<<grid, 256, 0, stream>>>(hs, ofs, out, S, T, D);
}

// Round 9
// 23.834 us; speedup vs baseline: 2.4269x; 1.0094x over previous
//
#include <hip/hip_runtime.h>

// WordPooler, single-dispatch, wave-per-2-words, 64-ary search (2 dependent
// load rounds), deep-MLP payload (8 loads in flight before 8 NT stores).
// Offsets sorted ascending per row (PAD=-100 only in the tail) -> each word is
// one run -> reference's scatter-mean == "copy first subword row, else zeros".
//
// Grid = 8192 waves = exactly 32 waves/CU on 256 CUs: whole grid co-resident,
// no dispatch tail, and each wave keeps 8 independent float4 loads in flight.
// Coarse search round is shared by both words (same probes, two ballots).
// Payload loads are issued unconditionally (index clamped, result zeroed for
// absent words) so the memory pipe never stalls on the presence branch.

typedef float v4f __attribute__((ext_vector_type(4)));

__global__ void __launch_bounds__(256)
wp_search_gather2(const float* __restrict__ hs, const int* __restrict__ ofs,
                  float* __restrict__ out, int S, int T, int D) {
    const int wave = threadIdx.x >> 6;
    const int lane = threadIdx.x & 63;
    const int b  = blockIdx.y;
    const int t0 = (blockIdx.x * 4 + wave) * 2;   // two consecutive words
    const int t1 = t0 + 1;

    const int* __restrict__ row = ofs + (size_t)b * S;
    const int stride = (S + 63) >> 6;             // 64 for S=4096

    // ---- Round 1 (shared): coarse bracket for both words.
    int idx1 = lane * stride;
    int k1 = 0x7fffffff;
    if (idx1 < S) { int v = row[idx1]; k1 = (v < 0) ? 0x7fffffff : v; }
    const int n1a = __popcll(__ballot(k1 < t0));
    const int n1b = __popcll(__ballot(k1 < t1));
    const int base_a = (n1a == 0) ? 0 : (n1a - 1) * stride + 1;
    const int base_b = (n1b == 0) ? 0 : (n1b - 1) * stride + 1;

    // ---- Round 2a: fine probe for t0 (lb in [base_a, base_a+63]).
    int ia = base_a + lane;
    int ka = 0x7fffffff;
    if (ia < S) { int v = row[ia]; ka = (v < 0) ? 0x7fffffff : v; }
    const int n2a = __popcll(__ballot(ka < t0));
    const bool pa = (__ballot(ka == t0) >> n2a) & 1ULL;
    const int sa = base_a + n2a;                  // first token of t0 if pa

    // ---- Round 2b: fine probe for t1 (probes usually L1-dup of 2a).
    int ib = base_b + lane;
    int kb = 0x7fffffff;
    if (ib < S) { int v = row[ib]; kb = (v < 0) ? 0x7fffffff : v; }
    const int n2b = __popcll(__ballot(kb < t1));
    const bool pb = (__ballot(kb == t1) >> n2b) & 1ULL;
    const int sb = base_b + n2b;

    // ---- Payload: 8 unconditional loads (clamped), then select, then store.
    const int ra = pa ? sa : 0;                   // clamp keeps load in-bounds
    const int rb = pb ? sb : 0;
    const v4f* __restrict__ inA = (const v4f*)(hs + ((size_t)b * S + ra) * (size_t)D);
    const v4f* __restrict__ inB = (const v4f*)(hs + ((size_t)b * S + rb) * (size_t)D);

    v4f a0 = inA[lane];
    v4f a1 = inA[lane + 64];
    v4f a2 = inA[lane + 128];
    v4f a3 = inA[lane + 192];
    v4f b0 = inB[lane];
    v4f b1 = inB[lane + 64];
    v4f b2 = inB[lane + 128];
    v4f b3 = inB[lane + 192];

    const v4f z = (v4f)(0.f);
    if (!pa) { a0 = z; a1 = z; a2 = z; a3 = z; }
    if (!pb) { b0 = z; b1 = z; b2 = z; b3 = z; }

    v4f* __restrict__ oA = (v4f*)(out + ((size_t)b * T + t0) * (size_t)D);
    v4f* __restrict__ oB = (v4f*)(out + ((size_t)b * T + t1) * (size_t)D);
    __builtin_nontemporal_store(a0, oA + lane);
    __builtin_nontemporal_store(a1, oA + lane + 64);
    __builtin_nontemporal_store(a2, oA + lane + 128);
    __builtin_nontemporal_store(a3, oA + lane + 192);
    __builtin_nontemporal_store(b0, oB + lane);
    __builtin_nontemporal_store(b1, oB + lane + 64);
    __builtin_nontemporal_store(b2, oB + lane + 128);
    __builtin_nontemporal_store(b3, oB + lane + 192);
}

extern "C" void kernel_launch(void* const* d_in, const int* in_sizes, int n_in,
                              void* d_out, int out_size, void* d_ws, size_t ws_size,
                              hipStream_t stream) {
    const float* hs  = (const float*)d_in[0];   // (B,S,D) f32
    const int*   ofs = (const int*)d_in[1];     // (B,S) int32
    float* out = (float*)d_out;                 // (B,T,D) f32

    const int B = 8;
    const int BS = in_sizes[1];
    const int S = BS / B;
    const int D = in_sizes[0] / BS;
    const int T = out_size / (B * D);

    dim3 grid(T / 8, B);                        // 256 x 8 blocks, 2 words/wave
    wp_search_gather2<<<grid, 256, 0, stream>>>(hs, ofs, out, S, T, D);
}